// Round 4
// baseline (114.620 us; speedup 1.0000x reference)
//
#include <hip/hip_runtime.h>

// out0 = 0.5*(1 + cos(th)*cos(x0) - sin(th)*sin(x0)*sin(x1))
// out1 = 0.5*(1 + cos(x0)*cos(x1))
// Product-to-sum: with u = x0+x1, v = x0-x1:
//   s0*s1 = 0.5*(cos(v) - cos(u)),  c0*c1 = 0.5*(cos(u) + cos(v))
// -> 3 cos per batch element (6 per float4) instead of 4 sincos pairs.
//
// R1/R2 lesson: nontemporal loads/stores REGRESS (110.6 -> 116.2 us).
// R3 lesson: 2-stream per-thread MLP is NEUTRAL (TLP already covers
//            latency at this occupancy).
// R4: capped-grid grid-stride (2048 blocks = 256 CU x 8) amortizes the
// per-block prologue (kernarg s_load, theta load, 2 trans, addressing)
// over 8 iterations; 4-way batched body keeps 4 dwordx4 loads in flight.

__device__ __forceinline__ float4 qc_elem(float4 v, float ct, float st) {
    float c0  = __cosf(v.x);
    float cu0 = __cosf(v.x + v.y);
    float cv0 = __cosf(v.x - v.y);
    float c1  = __cosf(v.z);
    float cu1 = __cosf(v.z + v.w);
    float cv1 = __cosf(v.z - v.w);
    float4 o;
    o.x = 0.5f + 0.5f * ct * c0 - 0.25f * st * (cv0 - cu0);
    o.y = 0.5f + 0.25f * (cu0 + cv0);
    o.z = 0.5f + 0.5f * ct * c1 - 0.25f * st * (cv1 - cu1);
    o.w = 0.5f + 0.25f * (cu1 + cv1);
    return o;
}

__global__ __launch_bounds__(256) void qc_kernel(
    const float4* __restrict__ x4,
    const float* __restrict__ theta,
    float4* __restrict__ out4,
    int n4)
{
    int tid = blockIdx.x * blockDim.x + threadIdx.x;
    int T   = gridDim.x * blockDim.x;

    // theta is wave-uniform; broadcast load + 2 transcendentals, hoisted
    float th = theta[0];
    float ct = __cosf(th);
    float st = __sinf(th);

    int i = tid;
    // 4-way batched main loop: 4 independent loads in flight per thread
    for (; i + 3 * T < n4; i += 4 * T) {
        float4 a = x4[i];
        float4 b = x4[i + T];
        float4 c = x4[i + 2 * T];
        float4 d = x4[i + 3 * T];
        float4 oa = qc_elem(a, ct, st);
        float4 ob = qc_elem(b, ct, st);
        float4 oc = qc_elem(c, ct, st);
        float4 od = qc_elem(d, ct, st);
        out4[i]         = oa;
        out4[i + T]     = ob;
        out4[i + 2 * T] = oc;
        out4[i + 3 * T] = od;
    }
    // tail (empty when n4 is a multiple of 4*T)
    for (; i < n4; i += T) {
        out4[i] = qc_elem(x4[i], ct, st);
    }
}

extern "C" void kernel_launch(void* const* d_in, const int* in_sizes, int n_in,
                              void* d_out, int out_size, void* d_ws, size_t ws_size,
                              hipStream_t stream) {
    const float* x     = (const float*)d_in[0];  // [B,2] flat
    const float* theta = (const float*)d_in[1];  // [1]
    float* out         = (float*)d_out;          // [B,2] flat

    int n  = in_sizes[0];      // total floats = 2*B (divisible by 4)
    int n4 = n / 4;

    const int block = 256;
    int grid = (n4 + block - 1) / block;
    if (grid > 2048) grid = 2048;   // 256 CU x 8 blocks/CU, grid-stride the rest

    qc_kernel<<<grid, block, 0, stream>>>(
        (const float4*)x, theta, (float4*)out, n4);
}

// Round 5
// 109.729 us; speedup vs baseline: 1.0446x; 1.0446x over previous
//
#include <hip/hip_runtime.h>

// out0 = 0.5*(1 + cos(th)*cos(x0) - sin(th)*sin(x0)*sin(x1))
// out1 = 0.5*(1 + cos(x0)*cos(x1))
// Derived in closed form from the 2-qubit RY/CNOT/RY circuit.
// Memory-bound streaming: 16 B in + 16 B out per thread (2 batch elems).
//
// Session record (MI355X, total dur_us incl. ~83 us harness re-poison fills):
//   R0 flat float4 (this kernel):        110.6  <- BEST
//   R2 nontemporal ld/st + 6-cos:        116.2  (nt regresses on gfx950)
//   R3 2-stream per-thread MLP:          111.3  (neutral; TLP suffices)
//   R4 capped grid-stride, 4-way batch:  114.6  (loop overhead regresses)
// Kernel share ~28 us vs ~21 us copy-roofline (134 MB @ 6.4 TB/s);
// gap is short-dispatch ramp/drain, not access pattern. At roofline.

__global__ __launch_bounds__(256) void qc_kernel(
    const float4* __restrict__ x4,
    const float* __restrict__ theta,
    float4* __restrict__ out4,
    int n4)
{
    int i = blockIdx.x * blockDim.x + threadIdx.x;
    if (i >= n4) return;

    // theta is wave-uniform; broadcast load + 2 transcendentals
    float th = theta[0];
    float ct = __cosf(th);
    float st = __sinf(th);

    float4 v = x4[i];  // (x0, x1, x0', x1') — two batch elements

    float s0 = __sinf(v.x), c0 = __cosf(v.x);
    float s1 = __sinf(v.y), c1 = __cosf(v.y);
    float s2 = __sinf(v.z), c2 = __cosf(v.z);
    float s3 = __sinf(v.w), c3 = __cosf(v.w);

    float4 o;
    o.x = 0.5f * (1.0f + ct * c0 - st * s0 * s1);
    o.y = 0.5f * (1.0f + c0 * c1);
    o.z = 0.5f * (1.0f + ct * c2 - st * s2 * s3);
    o.w = 0.5f * (1.0f + c2 * c3);

    out4[i] = o;
}

extern "C" void kernel_launch(void* const* d_in, const int* in_sizes, int n_in,
                              void* d_out, int out_size, void* d_ws, size_t ws_size,
                              hipStream_t stream) {
    const float* x     = (const float*)d_in[0];  // [B,2] flat
    const float* theta = (const float*)d_in[1];  // [1]
    float* out         = (float*)d_out;          // [B,2] flat

    int n  = in_sizes[0];      // total floats = 2*B (divisible by 4)
    int n4 = n / 4;

    const int block = 256;
    int grid = (n4 + block - 1) / block;

    qc_kernel<<<grid, block, 0, stream>>>(
        (const float4*)x, theta, (float4*)out, n4);
}